// Round 1
// baseline (176.887 us; speedup 1.0000x reference)
//
#include <hip/hip_runtime.h>

#define NN 768
#define IN_F 68
#define KNN 8
#define EO 32
#define FEAT 264
#define HALF_FEAT 132
#define EMB 32
#define NPAIR 294528   // 768*767/2

// ---------------- Kernel A: top-8 neighbors (stable, jax top_k semantics) + EdgeConv1 ----
// one wave (64 threads) per node; grid (768, 2 graphs)
__global__ void __launch_bounds__(64) topk_ec1_kernel(
    const float* __restrict__ feat0, const float* __restrict__ feat1,
    const float* __restrict__ w1, const float* __restrict__ b1,
    const float* __restrict__ w2, const float* __restrict__ b2,
    int* __restrict__ idx_out, float* __restrict__ e1out)
{
  const int i = blockIdx.x, g = blockIdx.y;
  const float* __restrict__ feat = g ? feat1 : feat0;
  const int lane = threadIdx.x;

  __shared__ unsigned long long keys[64*8];
  __shared__ int nbr[8];
  __shared__ float gl[KNN*IN_F];
  __shared__ float hsh[EO];

  const float ca0 = feat[i*IN_F+0], ca1 = feat[i*IN_F+1],
              ca2 = feat[i*IN_F+2], ca3 = feat[i*IN_F+3];

  // each lane scans 12 candidates, keeps private sorted top-8 (strict <, stable)
  float bd[8]; int bidx[8];
#pragma unroll
  for (int k = 0; k < 8; k++) { bd[k] = 1e30f; bidx[k] = 0; }
  for (int j = lane; j < NN; j += 64) {
    const float* fj = feat + j*IN_F;
    float d = fabsf(ca0 - fj[0]);   // same sequential add order as ref sum(-1)
    d += fabsf(ca1 - fj[1]);
    d += fabsf(ca2 - fj[2]);
    d += fabsf(ca3 - fj[3]);
    if (d < bd[7]) {
#pragma unroll
      for (int k = 7; k >= 1; k--) {
        if (d < bd[k-1])    { bd[k] = bd[k-1]; bidx[k] = bidx[k-1]; }
        else if (d < bd[k]) { bd[k] = d;       bidx[k] = j; }
      }
      if (d < bd[0]) { bd[0] = d; bidx[0] = j; }
    }
  }
  // merge across lanes: 8 rounds of wave-min over packed (dist,idx) keys.
  // dist >= 0 so float bit pattern is order-preserving; lexicographic (d, idx)
  // min == jax stable top_k order.
#pragma unroll
  for (int k = 0; k < 8; k++)
    keys[lane*8+k] = ((unsigned long long)__float_as_uint(bd[k]) << 32) | (unsigned)bidx[k];
  __syncthreads();
  int pos = 0;
#pragma unroll
  for (int r = 0; r < 8; r++) {
    unsigned long long mykey = keys[lane*8 + pos];
    unsigned long long mn = mykey;
#pragma unroll
    for (int s = 32; s >= 1; s >>= 1) {
      unsigned long long o = __shfl_xor(mn, s, 64);
      mn = (o < mn) ? o : mn;
    }
    if (mykey == mn) pos++;          // winner pops its head (idx unique -> one winner)
    if (lane == 0) {
      int nb = (int)(mn & 0xffffffffull);
      nbr[r] = nb;
      idx_out[(g*NN+i)*8 + r] = nb;
    }
  }
  __syncthreads();

  // gather neighbor features: gl[k*68+c] = feat[nbr[k]][c]
  for (int z = lane; z < KNN*IN_F; z += 64) {
    int k = z / IN_F, c = z - k*IN_F;
    gl[z] = feat[nbr[k]*IN_F + c];
  }
  __syncthreads();

  // layer1: h[e] = sum_{c,k} gl[k][c] * w1[(c*8+k)][e], split 544-sum across wave halves
  const int e = lane & 31, hf = lane >> 5;
  float acc = 0.f;
  const int cbeg = hf*34;
  for (int c = cbeg; c < cbeg+34; c++) {
#pragma unroll
    for (int k = 0; k < 8; k++)
      acc += gl[k*IN_F+c] * w1[(c*8+k)*EO + e];
  }
  acc += __shfl_xor(acc, 32, 64);
  if (hf == 0) {
    float h = acc + b1[e];
    hsh[e] = h >= 0.f ? h : 0.01f*h;
  }
  __syncthreads();
  if (lane < 32) {
    float o = b2[lane];
#pragma unroll
    for (int m = 0; m < 32; m++) o += hsh[m] * w2[m*EO + lane];
    o = o >= 0.f ? o : 0.01f*o;
    e1out[(g*NN+i)*EO + lane] = o;
  }
}

// ---------------- Kernel B: EdgeConv2 (gather e1 of neighbors) ----------------
__global__ void __launch_bounds__(64) ec2_kernel(
    const int* __restrict__ idx, const float* __restrict__ e1,
    const float* __restrict__ w1, const float* __restrict__ b1,
    const float* __restrict__ w2, const float* __restrict__ b2,
    float* __restrict__ e2out)
{
  const int i = blockIdx.x, g = blockIdx.y;
  const int lane = threadIdx.x;
  __shared__ float gl[KNN*EO];
  __shared__ float hsh[EO];
  for (int z = lane; z < KNN*EO; z += 64) {
    int k = z >> 5, c = z & 31;
    int nb = idx[(g*NN+i)*8 + k];
    gl[z] = e1[(g*NN+nb)*EO + c];
  }
  __syncthreads();
  const int e = lane & 31, hf = lane >> 5;
  float acc = 0.f;
  const int cbeg = hf*16;
  for (int c = cbeg; c < cbeg+16; c++) {
#pragma unroll
    for (int k = 0; k < 8; k++)
      acc += gl[k*EO+c] * w1[(c*8+k)*EO + e];
  }
  acc += __shfl_xor(acc, 32, 64);
  if (hf == 0) {
    float h = acc + b1[e];
    hsh[e] = h >= 0.f ? h : 0.01f*h;
  }
  __syncthreads();
  if (lane < 32) {
    float o = b2[lane];
#pragma unroll
    for (int m = 0; m < 32; m++) o += hsh[m] * w2[m*EO + lane];
    o = o >= 0.f ? o : 0.01f*o;
    e2out[(g*NN+i)*EO + lane] = o;
  }
}

// ---------------- Kernel C: BN stats via weighted node sums ----------------
// pair-matrix column c (<132) = x[i][c] with multiplicity (767-i) ; column 132+c
// = x[i][c] with multiplicity i ; summed over both graphs. fp64 accumulation.
__global__ void __launch_bounds__(256) stats_kernel(
    const float* __restrict__ feat0, const float* __restrict__ feat1,
    const float* __restrict__ e1, const float* __restrict__ e2,
    const float* __restrict__ bn_g,
    float* __restrict__ mu_out, float* __restrict__ sg_out)
{
  const int c = blockIdx.x;   // 0..131
  const int tid = threadIdx.x;
  double s1=0, s2=0, q1=0, q2=0;
  for (int t = tid; t < 2*NN; t += 256) {
    int g = t >= NN;
    int i = t - g*NN;
    float val;
    if (c < IN_F)      val = (g ? feat1 : feat0)[i*IN_F + c];
    else if (c < 100)  val = e1[(g*NN+i)*EO + (c-IN_F)];
    else               val = e2[(g*NN+i)*EO + (c-100)];
    double dv = val;
    double wf = (double)(NN-1-i), wsnd = (double)i;
    s1 += wf*dv;  s2 += wsnd*dv;
    double dq = dv*dv;
    q1 += wf*dq;  q2 += wsnd*dq;
  }
  __shared__ double sm[256];
  double sums[4] = {s1, s2, q1, q2};
  double tot[4];
#pragma unroll
  for (int z = 0; z < 4; z++) {
    __syncthreads();
    sm[tid] = sums[z];
    __syncthreads();
    for (int off = 128; off >= 1; off >>= 1) {
      if (tid < off) sm[tid] += sm[tid+off];
      __syncthreads();
    }
    tot[z] = sm[0];
  }
  if (tid == 0) {
    const double M2 = 2.0 * (double)NPAIR;
    double mu1 = tot[0]/M2, mu2 = tot[1]/M2;
    double v1 = tot[2]/M2 - mu1*mu1;
    double v2 = tot[3]/M2 - mu2*mu2;
    mu_out[c]           = (float)mu1;
    mu_out[HALF_FEAT+c] = (float)mu2;
    sg_out[c]           = (float)((double)bn_g[c] / sqrt(v1 + 1e-5));
    sg_out[HALF_FEAT+c] = (float)((double)bn_g[HALF_FEAT+c] / sqrt(v2 + 1e-5));
  }
}

// ---------------- Kernel D: per-node u/v = x @ (scaled W1 halves), plus c0 ----
__global__ void __launch_bounds__(64) uv_c0_kernel(
    const float* __restrict__ feat0, const float* __restrict__ feat1,
    const float* __restrict__ e1, const float* __restrict__ e2,
    const float* __restrict__ sg, const float* __restrict__ mu,
    const float* __restrict__ bn_b,
    const float* __restrict__ lin1_w, const float* __restrict__ lin1_b,
    float* __restrict__ u, float* __restrict__ v, float* __restrict__ c0g)
{
  const int i = blockIdx.x, g = blockIdx.y;
  const int t = threadIdx.x;
  if (i == NN) {               // one extra block computes the constant vector
    if (g == 0 && t < EMB) {
      float acc = lin1_b[t];
      for (int c = 0; c < FEAT; c++)
        acc += (bn_b[c] - mu[c]*sg[c]) * lin1_w[c*EMB + t];
      c0g[t] = acc;
    }
    return;
  }
  __shared__ float x[HALF_FEAT];
  for (int c = t; c < IN_F; c += 64) x[c] = (g ? feat1 : feat0)[i*IN_F + c];
  if (t < 32) x[IN_F + t]     = e1[(g*NN+i)*EO + t];
  else        x[100 + (t-32)] = e2[(g*NN+i)*EO + (t-32)];
  __syncthreads();
  const int e = t & 31, hf = t >> 5;
  const int base = hf * HALF_FEAT;   // half 0 -> u (first 132 cols), half 1 -> v
  float acc = 0.f;
  for (int c = 0; c < HALF_FEAT; c++)
    acc += x[c] * sg[base+c] * lin1_w[(base+c)*EMB + e];
  float* dst = hf ? v : u;
  dst[(g*NN+i)*EMB + e] = acc;
}

// ---------------- Kernel E: pair MLP over upper triangle ----------------
// 16x16 (i,j) tile per block; u/v rows staged in LDS; W2/W3/b/c0 read with
// uniform addresses (compiler scalarizes to s_load).
__global__ void __launch_bounds__(256) pair_kernel(
    const float* __restrict__ u, const float* __restrict__ v,
    const float* __restrict__ c0g,
    const float* __restrict__ lin2_w, const float* __restrict__ lin2_b,
    const float* __restrict__ lin3_w, const float* __restrict__ lin3_b,
    float2* __restrict__ out)
{
  const int g = blockIdx.y;
  int rem = blockIdx.x;        // 0..1175 triangular tile id
  int a = 0;
  while (rem >= 48 - a) { rem -= 48 - a; a++; }
  const int b = a + rem;

  __shared__ float su[512], sv[512];
  const int tid = threadIdx.x;
  const float* ub = u + (g*NN + a*16)*EMB;
  const float* vb = v + (g*NN + b*16)*EMB;
  su[tid] = ub[tid]; su[tid+256] = ub[tid+256];
  sv[tid] = vb[tid]; sv[tid+256] = vb[tid+256];
  __syncthreads();

  const int tx = tid & 15, ty = tid >> 4;
  const int i = a*16 + ty, j = b*16 + tx;
  if (j <= i) return;

  float h1[32];
#pragma unroll
  for (int e = 0; e < 32; e++) {
    float s = su[ty*32+e] + sv[tx*32+e] + c0g[e];
    h1[e] = s >= 0.f ? s : 0.01f*s;
  }
  float h2[32];
#pragma unroll
  for (int e = 0; e < 32; e++) h2[e] = lin2_b[e];
#pragma unroll
  for (int m = 0; m < 32; m++) {
    float hm = h1[m];
#pragma unroll
    for (int e = 0; e < 32; e++) h2[e] += hm * lin2_w[m*32+e];
  }
  float o0 = lin3_b[0], o1 = lin3_b[1];
#pragma unroll
  for (int m = 0; m < 32; m++) {
    float h = h2[m] >= 0.f ? h2[m] : 0.01f*h2[m];
    o0 += h * lin3_w[m*2+0];
    o1 += h * lin3_w[m*2+1];
  }
  long p = (long)i*NN - (long)i*(i+1)/2 + (j - i - 1);   // triu row-major index
  out[(long)g*NPAIR + p] = make_float2(o0, o1);
}

extern "C" void kernel_launch(void* const* d_in, const int* in_sizes, int n_in,
                              void* d_out, int out_size, void* d_ws, size_t ws_size,
                              hipStream_t stream)
{
  const float* feat0  = (const float*)d_in[0];
  const float* feat1  = (const float*)d_in[1];
  const float* ec1_w1 = (const float*)d_in[2];
  const float* ec1_b1 = (const float*)d_in[3];
  const float* ec1_w2 = (const float*)d_in[4];
  const float* ec1_b2 = (const float*)d_in[5];
  const float* ec2_w1 = (const float*)d_in[6];
  const float* ec2_b1 = (const float*)d_in[7];
  const float* ec2_w2 = (const float*)d_in[8];
  const float* ec2_b2 = (const float*)d_in[9];
  const float* bn_g   = (const float*)d_in[10];
  const float* bn_b   = (const float*)d_in[11];
  const float* lin1_w = (const float*)d_in[12];
  const float* lin1_b = (const float*)d_in[13];
  const float* lin2_w = (const float*)d_in[14];
  const float* lin2_b = (const float*)d_in[15];
  const float* lin3_w = (const float*)d_in[16];
  const float* lin3_b = (const float*)d_in[17];

  // workspace layout (all 16B aligned, total ~838 KB)
  char* ws = (char*)d_ws;
  int*   idx = (int*)  (ws + 0);        // 2*768*8 int      = 49152 B
  float* e1  = (float*)(ws + 49152);    // 2*768*32 f32     = 196608 B
  float* e2  = (float*)(ws + 245760);   // 196608 B
  float* u   = (float*)(ws + 442368);   // 196608 B
  float* v   = (float*)(ws + 638976);   // 196608 B
  float* mu  = (float*)(ws + 835584);   // 264 f32
  float* sg  = (float*)(ws + 836640);   // 264 f32
  float* c0g = (float*)(ws + 837696);   // 32 f32

  topk_ec1_kernel<<<dim3(768,2), 64, 0, stream>>>(feat0, feat1, ec1_w1, ec1_b1,
                                                  ec1_w2, ec1_b2, idx, e1);
  ec2_kernel<<<dim3(768,2), 64, 0, stream>>>(idx, e1, ec2_w1, ec2_b1,
                                             ec2_w2, ec2_b2, e2);
  stats_kernel<<<dim3(132), 256, 0, stream>>>(feat0, feat1, e1, e2, bn_g, mu, sg);
  uv_c0_kernel<<<dim3(769,2), 64, 0, stream>>>(feat0, feat1, e1, e2, sg, mu, bn_b,
                                               lin1_w, lin1_b, u, v, c0g);
  pair_kernel<<<dim3(1176,2), 256, 0, stream>>>(u, v, c0g, lin2_w, lin2_b,
                                                lin3_w, lin3_b, (float2*)d_out);
}

// Round 2
// 150.892 us; speedup vs baseline: 1.1723x; 1.1723x over previous
//
#include <hip/hip_runtime.h>

#define NN 768
#define IN_F 68
#define KNN 8
#define EO 32
#define FEAT 264
#define HALF_FEAT 132
#define EMB 32
#define NPAIR 294528   // 768*767/2

// ---------------- Kernel A: top-8 neighbors (stable, jax top_k semantics) + EdgeConv1 ----
// one wave (64 threads) per node; grid (768, 2 graphs)
// candidates held in float4 registers (feat row = 272B, 16B-aligned)
__global__ void __launch_bounds__(64) topk_ec1_kernel(
    const float* __restrict__ feat0, const float* __restrict__ feat1,
    const float* __restrict__ w1, const float* __restrict__ b1,
    const float* __restrict__ w2, const float* __restrict__ b2,
    int* __restrict__ idx_out, float* __restrict__ e1out)
{
  const int i = blockIdx.x, g = blockIdx.y;
  const float* __restrict__ feat = g ? feat1 : feat0;
  const int lane = threadIdx.x;

  __shared__ unsigned long long keys[64*8];
  __shared__ int nbr[8];
  __shared__ float gl[KNN*IN_F];
  __shared__ float hsh[EO];

  const float4 ci = *(const float4*)(feat + i*IN_F);

  // 12 candidates per lane, loaded as independent float4s (pipelined)
  float4 cand[12];
#pragma unroll
  for (int t = 0; t < 12; t++)
    cand[t] = *(const float4*)(feat + (lane + 64*t)*IN_F);

  // private sorted top-8 (strict <, stable)
  float bd[8]; int bidx[8];
#pragma unroll
  for (int k = 0; k < 8; k++) { bd[k] = 1e30f; bidx[k] = 0; }
#pragma unroll
  for (int t = 0; t < 12; t++) {
    const int j = lane + 64*t;
    float d = fabsf(ci.x - cand[t].x);   // same sequential add order as ref sum(-1)
    d += fabsf(ci.y - cand[t].y);
    d += fabsf(ci.z - cand[t].z);
    d += fabsf(ci.w - cand[t].w);
    if (d < bd[7]) {
#pragma unroll
      for (int k = 7; k >= 1; k--) {
        if (d < bd[k-1])    { bd[k] = bd[k-1]; bidx[k] = bidx[k-1]; }
        else if (d < bd[k]) { bd[k] = d;       bidx[k] = j; }
      }
      if (d < bd[0]) { bd[0] = d; bidx[0] = j; }
    }
  }
  // merge across lanes: 8 rounds of wave-min over packed (dist,idx) keys.
  // dist >= 0 so float bit pattern is order-preserving; lexicographic (d, idx)
  // min == jax stable top_k order.
#pragma unroll
  for (int k = 0; k < 8; k++)
    keys[lane*8+k] = ((unsigned long long)__float_as_uint(bd[k]) << 32) | (unsigned)bidx[k];
  __syncthreads();
  int pos = 0;
#pragma unroll
  for (int r = 0; r < 8; r++) {
    unsigned long long mykey = keys[lane*8 + pos];
    unsigned long long mn = mykey;
#pragma unroll
    for (int s = 32; s >= 1; s >>= 1) {
      unsigned long long o = __shfl_xor(mn, s, 64);
      mn = (o < mn) ? o : mn;
    }
    if (mykey == mn) pos++;          // winner pops its head (idx unique -> one winner)
    if (lane == 0) {
      int nb = (int)(mn & 0xffffffffull);
      nbr[r] = nb;
      idx_out[(g*NN+i)*8 + r] = nb;
    }
  }
  __syncthreads();

  // gather neighbor features as float4: gl[k][q*4..] = feat[nbr[k]][q*4..]
  for (int z = lane; z < KNN*17; z += 64) {
    int k = z / 17, q = z - k*17;
    *(float4*)&gl[k*IN_F + q*4] = *(const float4*)(feat + nbr[k]*IN_F + q*4);
  }
  __syncthreads();

  // layer1: h[e] = sum_{c,k} gl[k][c] * w1[(c*8+k)][e], split 544-sum across wave halves
  const int e = lane & 31, hf = lane >> 5;
  float acc = 0.f;
  const int cbeg = hf*34;
  for (int c = cbeg; c < cbeg+34; c++) {
#pragma unroll
    for (int k = 0; k < 8; k++)
      acc += gl[k*IN_F+c] * w1[(c*8+k)*EO + e];
  }
  acc += __shfl_xor(acc, 32, 64);
  if (hf == 0) {
    float h = acc + b1[e];
    hsh[e] = fmaxf(h, 0.01f*h);
  }
  __syncthreads();
  if (lane < 32) {
    float o = b2[lane];
#pragma unroll
    for (int m = 0; m < 32; m++) o += hsh[m] * w2[m*EO + lane];
    o = fmaxf(o, 0.01f*o);
    e1out[(g*NN+i)*EO + lane] = o;
  }
}

// ---------------- Kernel B: EdgeConv2 (gather e1 of neighbors) ----------------
__global__ void __launch_bounds__(64) ec2_kernel(
    const int* __restrict__ idx, const float* __restrict__ e1,
    const float* __restrict__ w1, const float* __restrict__ b1,
    const float* __restrict__ w2, const float* __restrict__ b2,
    float* __restrict__ e2out)
{
  const int i = blockIdx.x, g = blockIdx.y;
  const int lane = threadIdx.x;
  __shared__ float gl[KNN*EO];
  __shared__ float hsh[EO];
  {
    // 8 neighbors x 8 float4 = 64 vector loads, one per lane
    const int k = lane >> 3, q = lane & 7;
    const int nb = idx[(g*NN+i)*8 + k];
    *(float4*)&gl[k*EO + q*4] = *(const float4*)(e1 + (g*NN+nb)*EO + q*4);
  }
  __syncthreads();
  const int e = lane & 31, hf = lane >> 5;
  float acc = 0.f;
  const int cbeg = hf*16;
  for (int c = cbeg; c < cbeg+16; c++) {
#pragma unroll
    for (int k = 0; k < 8; k++)
      acc += gl[k*EO+c] * w1[(c*8+k)*EO + e];
  }
  acc += __shfl_xor(acc, 32, 64);
  if (hf == 0) {
    float h = acc + b1[e];
    hsh[e] = fmaxf(h, 0.01f*h);
  }
  __syncthreads();
  if (lane < 32) {
    float o = b2[lane];
#pragma unroll
    for (int m = 0; m < 32; m++) o += hsh[m] * w2[m*EO + lane];
    o = fmaxf(o, 0.01f*o);
    e2out[(g*NN+i)*EO + lane] = o;
  }
}

// ---------------- Kernel C: BN stats via weighted node sums ----------------
// pair-matrix column c (<132) = x[i][c] with multiplicity (767-i) ; column 132+c
// = x[i][c] with multiplicity i ; summed over both graphs. fp64 accumulation.
__global__ void __launch_bounds__(256) stats_kernel(
    const float* __restrict__ feat0, const float* __restrict__ feat1,
    const float* __restrict__ e1, const float* __restrict__ e2,
    const float* __restrict__ bn_g,
    float* __restrict__ mu_out, float* __restrict__ sg_out)
{
  const int c = blockIdx.x;   // 0..131
  const int tid = threadIdx.x;
  double s1=0, s2=0, q1=0, q2=0;
  for (int t = tid; t < 2*NN; t += 256) {
    int g = t >= NN;
    int i = t - g*NN;
    float val;
    if (c < IN_F)      val = (g ? feat1 : feat0)[i*IN_F + c];
    else if (c < 100)  val = e1[(g*NN+i)*EO + (c-IN_F)];
    else               val = e2[(g*NN+i)*EO + (c-100)];
    double dv = val;
    double wf = (double)(NN-1-i), wsnd = (double)i;
    s1 += wf*dv;  s2 += wsnd*dv;
    double dq = dv*dv;
    q1 += wf*dq;  q2 += wsnd*dq;
  }
  __shared__ double sm[256];
  double sums[4] = {s1, s2, q1, q2};
  double tot[4];
#pragma unroll
  for (int z = 0; z < 4; z++) {
    __syncthreads();
    sm[tid] = sums[z];
    __syncthreads();
    for (int off = 128; off >= 1; off >>= 1) {
      if (tid < off) sm[tid] += sm[tid+off];
      __syncthreads();
    }
    tot[z] = sm[0];
  }
  if (tid == 0) {
    const double M2 = 2.0 * (double)NPAIR;
    double mu1 = tot[0]/M2, mu2 = tot[1]/M2;
    double v1 = tot[2]/M2 - mu1*mu1;
    double v2 = tot[3]/M2 - mu2*mu2;
    mu_out[c]           = (float)mu1;
    mu_out[HALF_FEAT+c] = (float)mu2;
    sg_out[c]           = (float)((double)bn_g[c] / sqrt(v1 + 1e-5));
    sg_out[HALF_FEAT+c] = (float)((double)bn_g[HALF_FEAT+c] / sqrt(v2 + 1e-5));
  }
}

// ---------------- Kernel D: per-node u/v = x @ (scaled W1 halves), plus c0 ----
__global__ void __launch_bounds__(64) uv_c0_kernel(
    const float* __restrict__ feat0, const float* __restrict__ feat1,
    const float* __restrict__ e1, const float* __restrict__ e2,
    const float* __restrict__ sg, const float* __restrict__ mu,
    const float* __restrict__ bn_b,
    const float* __restrict__ lin1_w, const float* __restrict__ lin1_b,
    float* __restrict__ u, float* __restrict__ v, float* __restrict__ c0g)
{
  const int i = blockIdx.x, g = blockIdx.y;
  const int t = threadIdx.x;
  if (i == NN) {               // one extra block computes the constant vector
    if (g == 0 && t < EMB) {
      float acc = lin1_b[t];
      for (int c = 0; c < FEAT; c++)
        acc += (bn_b[c] - mu[c]*sg[c]) * lin1_w[c*EMB + t];
      c0g[t] = acc;
    }
    return;
  }
  __shared__ float x[HALF_FEAT];
  for (int c = t; c < IN_F; c += 64) x[c] = (g ? feat1 : feat0)[i*IN_F + c];
  if (t < 32) x[IN_F + t]     = e1[(g*NN+i)*EO + t];
  else        x[100 + (t-32)] = e2[(g*NN+i)*EO + (t-32)];
  __syncthreads();
  const int e = t & 31, hf = t >> 5;
  const int base = hf * HALF_FEAT;   // half 0 -> u (first 132 cols), half 1 -> v
  float acc = 0.f;
  for (int c = 0; c < HALF_FEAT; c++)
    acc += x[c] * sg[base+c] * lin1_w[(base+c)*EMB + e];
  float* dst = hf ? v : u;
  dst[(g*NN+i)*EMB + e] = acc;
}

// ---------------- Kernel E: pair MLP over upper triangle ----------------
// 16x16 (i,j) tile per block; u/v rows staged in LDS with stride 36
// (16B-aligned so ds_read_b128 forms; 4*tx+e banks are at worst 2-way
// aliased which is free). W2/W3/b/c0 uniform -> scalarized s_load.
__global__ void __launch_bounds__(256) pair_kernel(
    const float* __restrict__ u, const float* __restrict__ v,
    const float* __restrict__ c0g,
    const float* __restrict__ lin2_w, const float* __restrict__ lin2_b,
    const float* __restrict__ lin3_w, const float* __restrict__ lin3_b,
    float2* __restrict__ out)
{
  const int g = blockIdx.y;
  int rem = blockIdx.x;        // 0..1175 triangular tile id
  int a = 0;
  while (rem >= 48 - a) { rem -= 48 - a; a++; }
  const int b = a + rem;

  __shared__ float su[16*36], sv[16*36];
  const int tid = threadIdx.x;
  {
    int r = tid >> 5, c = tid & 31;
    su[r*36+c] = u[(g*NN + a*16 + r)*EMB + c];
    sv[r*36+c] = v[(g*NN + b*16 + r)*EMB + c];
    r += 8;
    su[r*36+c] = u[(g*NN + a*16 + r)*EMB + c];
    sv[r*36+c] = v[(g*NN + b*16 + r)*EMB + c];
  }
  __syncthreads();

  const int tx = tid & 15, ty = tid >> 4;
  const int i = a*16 + ty, j = b*16 + tx;
  if (j <= i) return;

  float h1[32];
#pragma unroll
  for (int e = 0; e < 32; e++) {
    float s = su[ty*36+e] + sv[tx*36+e] + c0g[e];
    h1[e] = fmaxf(s, 0.01f*s);
  }
  float h2[32];
#pragma unroll
  for (int e = 0; e < 32; e++) h2[e] = lin2_b[e];
#pragma unroll
  for (int m = 0; m < 32; m++) {
    float hm = h1[m];
#pragma unroll
    for (int e = 0; e < 32; e++) h2[e] += hm * lin2_w[m*32+e];
  }
  float o0 = lin3_b[0], o1 = lin3_b[1];
#pragma unroll
  for (int m = 0; m < 32; m++) {
    float h = fmaxf(h2[m], 0.01f*h2[m]);
    o0 += h * lin3_w[m*2+0];
    o1 += h * lin3_w[m*2+1];
  }
  long p = (long)i*NN - (long)i*(i+1)/2 + (j - i - 1);   // triu row-major index
  out[(long)g*NPAIR + p] = make_float2(o0, o1);
}

extern "C" void kernel_launch(void* const* d_in, const int* in_sizes, int n_in,
                              void* d_out, int out_size, void* d_ws, size_t ws_size,
                              hipStream_t stream)
{
  const float* feat0  = (const float*)d_in[0];
  const float* feat1  = (const float*)d_in[1];
  const float* ec1_w1 = (const float*)d_in[2];
  const float* ec1_b1 = (const float*)d_in[3];
  const float* ec1_w2 = (const float*)d_in[4];
  const float* ec1_b2 = (const float*)d_in[5];
  const float* ec2_w1 = (const float*)d_in[6];
  const float* ec2_b1 = (const float*)d_in[7];
  const float* ec2_w2 = (const float*)d_in[8];
  const float* ec2_b2 = (const float*)d_in[9];
  const float* bn_g   = (const float*)d_in[10];
  const float* bn_b   = (const float*)d_in[11];
  const float* lin1_w = (const float*)d_in[12];
  const float* lin1_b = (const float*)d_in[13];
  const float* lin2_w = (const float*)d_in[14];
  const float* lin2_b = (const float*)d_in[15];
  const float* lin3_w = (const float*)d_in[16];
  const float* lin3_b = (const float*)d_in[17];

  // workspace layout (all 16B aligned, total ~838 KB)
  char* ws = (char*)d_ws;
  int*   idx = (int*)  (ws + 0);        // 2*768*8 int      = 49152 B
  float* e1  = (float*)(ws + 49152);    // 2*768*32 f32     = 196608 B
  float* e2  = (float*)(ws + 245760);   // 196608 B
  float* u   = (float*)(ws + 442368);   // 196608 B
  float* v   = (float*)(ws + 638976);   // 196608 B
  float* mu  = (float*)(ws + 835584);   // 264 f32
  float* sg  = (float*)(ws + 836640);   // 264 f32
  float* c0g = (float*)(ws + 837696);   // 32 f32

  topk_ec1_kernel<<<dim3(768,2), 64, 0, stream>>>(feat0, feat1, ec1_w1, ec1_b1,
                                                  ec1_w2, ec1_b2, idx, e1);
  ec2_kernel<<<dim3(768,2), 64, 0, stream>>>(idx, e1, ec2_w1, ec2_b1,
                                             ec2_w2, ec2_b2, e2);
  stats_kernel<<<dim3(132), 256, 0, stream>>>(feat0, feat1, e1, e2, bn_g, mu, sg);
  uv_c0_kernel<<<dim3(769,2), 64, 0, stream>>>(feat0, feat1, e1, e2, sg, mu, bn_b,
                                               lin1_w, lin1_b, u, v, c0g);
  pair_kernel<<<dim3(1176,2), 256, 0, stream>>>(u, v, c0g, lin2_w, lin2_b,
                                                lin3_w, lin3_b, (float2*)d_out);
}

// Round 3
// 139.240 us; speedup vs baseline: 1.2704x; 1.0837x over previous
//
#include <hip/hip_runtime.h>

#define NN 768
#define IN_F 68
#define KNN 8
#define EO 32
#define FEAT 264
#define HALF_FEAT 132
#define EMB 32
#define NPAIR 294528   // 768*767/2

typedef __attribute__((ext_vector_type(8))) short bf16x8;
typedef __attribute__((ext_vector_type(4))) float f32x4;

static __device__ __forceinline__ short f2bf(float x) {
  unsigned u = __float_as_uint(x);
  unsigned r = (u + 0x7fffu + ((u >> 16) & 1u)) >> 16;   // RNE
  return (short)r;
}
static __device__ __forceinline__ float bf2f(short h) {
  return __uint_as_float(((unsigned)(unsigned short)h) << 16);
}

// ---------------- Kernel A: top-8 neighbors (stable, jax top_k semantics) + EdgeConv1 ----
__global__ void __launch_bounds__(64) topk_ec1_kernel(
    const float* __restrict__ feat0, const float* __restrict__ feat1,
    const float* __restrict__ w1, const float* __restrict__ b1,
    const float* __restrict__ w2, const float* __restrict__ b2,
    int* __restrict__ idx_out, float* __restrict__ e1out)
{
  const int i = blockIdx.x, g = blockIdx.y;
  const float* __restrict__ feat = g ? feat1 : feat0;
  const int lane = threadIdx.x;

  __shared__ unsigned long long keys[64*8];
  __shared__ int nbr[8];
  __shared__ float gl[KNN*IN_F];
  __shared__ float hsh[EO];

  const float4 ci = *(const float4*)(feat + i*IN_F);

  float4 cand[12];
#pragma unroll
  for (int t = 0; t < 12; t++)
    cand[t] = *(const float4*)(feat + (lane + 64*t)*IN_F);

  float bd[8]; int bidx[8];
#pragma unroll
  for (int k = 0; k < 8; k++) { bd[k] = 1e30f; bidx[k] = 0; }
#pragma unroll
  for (int t = 0; t < 12; t++) {
    const int j = lane + 64*t;
    float d = fabsf(ci.x - cand[t].x);   // same sequential add order as ref sum(-1)
    d += fabsf(ci.y - cand[t].y);
    d += fabsf(ci.z - cand[t].z);
    d += fabsf(ci.w - cand[t].w);
    if (d < bd[7]) {
#pragma unroll
      for (int k = 7; k >= 1; k--) {
        if (d < bd[k-1])    { bd[k] = bd[k-1]; bidx[k] = bidx[k-1]; }
        else if (d < bd[k]) { bd[k] = d;       bidx[k] = j; }
      }
      if (d < bd[0]) { bd[0] = d; bidx[0] = j; }
    }
  }
#pragma unroll
  for (int k = 0; k < 8; k++)
    keys[lane*8+k] = ((unsigned long long)__float_as_uint(bd[k]) << 32) | (unsigned)bidx[k];
  __syncthreads();
  int pos = 0;
#pragma unroll
  for (int r = 0; r < 8; r++) {
    unsigned long long mykey = keys[lane*8 + pos];
    unsigned long long mn = mykey;
#pragma unroll
    for (int s = 32; s >= 1; s >>= 1) {
      unsigned long long o = __shfl_xor(mn, s, 64);
      mn = (o < mn) ? o : mn;
    }
    if (mykey == mn) pos++;
    if (lane == 0) {
      int nb = (int)(mn & 0xffffffffull);
      nbr[r] = nb;
      idx_out[(g*NN+i)*8 + r] = nb;
    }
  }
  __syncthreads();

  for (int z = lane; z < KNN*17; z += 64) {
    int k = z / 17, q = z - k*17;
    *(float4*)&gl[k*IN_F + q*4] = *(const float4*)(feat + nbr[k]*IN_F + q*4);
  }
  __syncthreads();

  const int e = lane & 31, hf = lane >> 5;
  float acc = 0.f;
  const int cbeg = hf*34;
  for (int c = cbeg; c < cbeg+34; c++) {
#pragma unroll
    for (int k = 0; k < 8; k++)
      acc += gl[k*IN_F+c] * w1[(c*8+k)*EO + e];
  }
  acc += __shfl_xor(acc, 32, 64);
  if (hf == 0) {
    float h = acc + b1[e];
    hsh[e] = fmaxf(h, 0.01f*h);
  }
  __syncthreads();
  if (lane < 32) {
    float o = b2[lane];
#pragma unroll
    for (int m = 0; m < 32; m++) o += hsh[m] * w2[m*EO + lane];
    o = fmaxf(o, 0.01f*o);
    e1out[(g*NN+i)*EO + lane] = o;
  }
}

// ---------------- Kernel B: EdgeConv2 ----------------
__global__ void __launch_bounds__(64) ec2_kernel(
    const int* __restrict__ idx, const float* __restrict__ e1,
    const float* __restrict__ w1, const float* __restrict__ b1,
    const float* __restrict__ w2, const float* __restrict__ b2,
    float* __restrict__ e2out)
{
  const int i = blockIdx.x, g = blockIdx.y;
  const int lane = threadIdx.x;
  __shared__ float gl[KNN*EO];
  __shared__ float hsh[EO];
  {
    const int k = lane >> 3, q = lane & 7;
    const int nb = idx[(g*NN+i)*8 + k];
    *(float4*)&gl[k*EO + q*4] = *(const float4*)(e1 + (g*NN+nb)*EO + q*4);
  }
  __syncthreads();
  const int e = lane & 31, hf = lane >> 5;
  float acc = 0.f;
  const int cbeg = hf*16;
  for (int c = cbeg; c < cbeg+16; c++) {
#pragma unroll
    for (int k = 0; k < 8; k++)
      acc += gl[k*EO+c] * w1[(c*8+k)*EO + e];
  }
  acc += __shfl_xor(acc, 32, 64);
  if (hf == 0) {
    float h = acc + b1[e];
    hsh[e] = fmaxf(h, 0.01f*h);
  }
  __syncthreads();
  if (lane < 32) {
    float o = b2[lane];
#pragma unroll
    for (int m = 0; m < 32; m++) o += hsh[m] * w2[m*EO + lane];
    o = fmaxf(o, 0.01f*o);
    e2out[(g*NN+i)*EO + lane] = o;
  }
}

// ---------------- Kernel C: BN stats (weighted node sums, shfl reduce) ----------------
__global__ void __launch_bounds__(256) stats_kernel(
    const float* __restrict__ feat0, const float* __restrict__ feat1,
    const float* __restrict__ e1, const float* __restrict__ e2,
    const float* __restrict__ bn_g,
    float* __restrict__ mu_out, float* __restrict__ sg_out)
{
  const int c = blockIdx.x;   // 0..131
  const int tid = threadIdx.x;
  double s1=0, s2=0, q1=0, q2=0;
  for (int t = tid; t < 2*NN; t += 256) {
    int g = t >= NN;
    int i = t - g*NN;
    float val;
    if (c < IN_F)      val = (g ? feat1 : feat0)[i*IN_F + c];
    else if (c < 100)  val = e1[(g*NN+i)*EO + (c-IN_F)];
    else               val = e2[(g*NN+i)*EO + (c-100)];
    double dv = val;
    double wf = (double)(NN-1-i), wsnd = (double)i;
    s1 += wf*dv;  s2 += wsnd*dv;
    double dq = dv*dv;
    q1 += wf*dq;  q2 += wsnd*dq;
  }
#pragma unroll
  for (int off = 32; off >= 1; off >>= 1) {
    s1 += __shfl_xor(s1, off, 64);
    s2 += __shfl_xor(s2, off, 64);
    q1 += __shfl_xor(q1, off, 64);
    q2 += __shfl_xor(q2, off, 64);
  }
  __shared__ double red[4][4];
  const int w = tid >> 6;
  if ((tid & 63) == 0) { red[w][0]=s1; red[w][1]=s2; red[w][2]=q1; red[w][3]=q2; }
  __syncthreads();
  if (tid == 0) {
    double t0 = red[0][0]+red[1][0]+red[2][0]+red[3][0];
    double t1 = red[0][1]+red[1][1]+red[2][1]+red[3][1];
    double t2 = red[0][2]+red[1][2]+red[2][2]+red[3][2];
    double t3 = red[0][3]+red[1][3]+red[2][3]+red[3][3];
    const double M2 = 2.0 * (double)NPAIR;
    double mu1 = t0/M2, mu2 = t1/M2;
    double v1 = t2/M2 - mu1*mu1;
    double v2 = t3/M2 - mu2*mu2;
    mu_out[c]           = (float)mu1;
    mu_out[HALF_FEAT+c] = (float)mu2;
    sg_out[c]           = (float)((double)bn_g[c] / sqrt(v1 + 1e-5));
    sg_out[HALF_FEAT+c] = (float)((double)bn_g[HALF_FEAT+c] / sqrt(v2 + 1e-5));
  }
}

// ---------------- Kernel D: per-node u/v, plus c0 ----------------
__global__ void __launch_bounds__(64) uv_c0_kernel(
    const float* __restrict__ feat0, const float* __restrict__ feat1,
    const float* __restrict__ e1, const float* __restrict__ e2,
    const float* __restrict__ sg, const float* __restrict__ mu,
    const float* __restrict__ bn_b,
    const float* __restrict__ lin1_w, const float* __restrict__ lin1_b,
    float* __restrict__ u, float* __restrict__ v, float* __restrict__ c0g)
{
  const int i = blockIdx.x, g = blockIdx.y;
  const int t = threadIdx.x;
  if (i == NN) {
    if (g == 0 && t < EMB) {
      float acc = lin1_b[t];
      for (int c = 0; c < FEAT; c++)
        acc += (bn_b[c] - mu[c]*sg[c]) * lin1_w[c*EMB + t];
      c0g[t] = acc;
    }
    return;
  }
  __shared__ float x[HALF_FEAT];
  for (int c = t; c < IN_F; c += 64) x[c] = (g ? feat1 : feat0)[i*IN_F + c];
  if (t < 32) x[IN_F + t]     = e1[(g*NN+i)*EO + t];
  else        x[100 + (t-32)] = e2[(g*NN+i)*EO + (t-32)];
  __syncthreads();
  const int e = t & 31, hf = t >> 5;
  const int base = hf * HALF_FEAT;
  float acc = 0.f;
  for (int c = 0; c < HALF_FEAT; c++)
    acc += x[c] * sg[base+c] * lin1_w[(base+c)*EMB + e];
  float* dst = hf ? v : u;
  dst[(g*NN+i)*EMB + e] = acc;
}

// ---------------- Kernel E: pair MLP via split-bf16 MFMA ----------------
// Block = 16x16 (a,b) node tile = 256 pairs, 4 waves. Wave w owns i-rows
// ty = 4w..4w+3; each row-tile is one M=16 MFMA tile (A rows = the 16 j-nodes).
// lin2 (K=32 -> N=32) done as 3 mfma_16x16x32_bf16 per N-half with hi/lo split
// (error ~2^-17, well under threshold). D -> per-wave LDS buffer -> lrelu+lin3
// in VALU. Intra-wave ds_write->ds_read ordered by lgkmcnt (no barrier needed).
__global__ void __launch_bounds__(256) pair_kernel(
    const float* __restrict__ u, const float* __restrict__ v,
    const float* __restrict__ c0g,
    const float* __restrict__ lin2_w, const float* __restrict__ lin2_b,
    const float* __restrict__ lin3_w, const float* __restrict__ lin3_b,
    float2* __restrict__ out)
{
  const int g = blockIdx.y;
  int rem = blockIdx.x;        // 0..1175 triangular tile id
  int a = 0;
  while (rem >= 48 - a) { rem -= 48 - a; a++; }
  const int b = a + rem;

  __shared__ float su[16*36], sv[16*36];
  __shared__ float wbuf[4][16*36];
  const int tid = threadIdx.x;
  {
    int r = tid >> 5, c = tid & 31;
    su[r*36+c] = u[(g*NN + a*16 + r)*EMB + c];
    sv[r*36+c] = v[(g*NN + b*16 + r)*EMB + c];
    r += 8;
    su[r*36+c] = u[(g*NN + a*16 + r)*EMB + c];
    sv[r*36+c] = v[(g*NN + b*16 + r)*EMB + c];
  }
  __syncthreads();

  const int lane = tid & 63, w = tid >> 6;
  const int q = lane & 15, kg = lane >> 4;   // q: m/n index, kg: k-group

  // W2 fragments (B operand: n = lane&15, k = kg*8+jj), hi/lo split
  bf16x8 whi0, wlo0, whi1, wlo1;
#pragma unroll
  for (int jj = 0; jj < 8; jj++) {
    float w0 = lin2_w[(kg*8+jj)*32 + q];
    float w1 = lin2_w[(kg*8+jj)*32 + 16 + q];
    short h0 = f2bf(w0); whi0[jj] = h0; wlo0[jj] = f2bf(w0 - bf2f(h0));
    short h1 = f2bf(w1); whi1[jj] = h1; wlo1[jj] = f2bf(w1 - bf2f(h1));
  }
  // sv + c0 for this lane's (m=q, k=kg*8+jj) — tile-invariant
  float svc[8];
#pragma unroll
  for (int jj = 0; jj < 8; jj++)
    svc[jj] = sv[q*36 + kg*8 + jj] + c0g[kg*8+jj];
  // epilogue constants for this lane's n-range
  float2 w3v[8]; float b2v[8];
#pragma unroll
  for (int jj = 0; jj < 8; jj++) {
    w3v[jj] = ((const float2*)lin3_w)[kg*8+jj];
    b2v[jj] = lin2_b[kg*8+jj];
  }
  const float b30 = lin3_b[0], b31 = lin3_b[1];

  float* wb = wbuf[w];
#pragma unroll
  for (int t = 0; t < 4; t++) {
    const int ty = w*4 + t;
    // A fragment: rows m = 16 j-nodes, k = embedding dim; hi/lo split of h1
    bf16x8 ahi, alo;
#pragma unroll
    for (int jj = 0; jj < 8; jj++) {
      float s = su[ty*36 + kg*8 + jj] + svc[jj];
      s = fmaxf(s, 0.01f*s);
      short hh = f2bf(s);
      ahi[jj] = hh; alo[jj] = f2bf(s - bf2f(hh));
    }
    f32x4 acc0 = {0.f,0.f,0.f,0.f}, acc1 = {0.f,0.f,0.f,0.f};
    acc0 = __builtin_amdgcn_mfma_f32_16x16x32_bf16(ahi, whi0, acc0, 0,0,0);
    acc1 = __builtin_amdgcn_mfma_f32_16x16x32_bf16(ahi, whi1, acc1, 0,0,0);
    acc0 = __builtin_amdgcn_mfma_f32_16x16x32_bf16(ahi, wlo0, acc0, 0,0,0);
    acc1 = __builtin_amdgcn_mfma_f32_16x16x32_bf16(ahi, wlo1, acc1, 0,0,0);
    acc0 = __builtin_amdgcn_mfma_f32_16x16x32_bf16(alo, whi0, acc0, 0,0,0);
    acc1 = __builtin_amdgcn_mfma_f32_16x16x32_bf16(alo, whi1, acc1, 0,0,0);
    // D layout: row m = kg*4+r, col n = q (acc0: n<16, acc1: n>=16)
#pragma unroll
    for (int r = 0; r < 4; r++) {
      wb[(kg*4+r)*36 + q]      = acc0[r];
      wb[(kg*4+r)*36 + 16 + q] = acc1[r];
    }
    // epilogue: lane handles pair m=q, n-range kg*8..kg*8+8
    float o0 = 0.f, o1 = 0.f;
#pragma unroll
    for (int jj = 0; jj < 8; jj++) {
      float h = wb[q*36 + kg*8 + jj] + b2v[jj];
      h = fmaxf(h, 0.01f*h);
      o0 += h * w3v[jj].x;
      o1 += h * w3v[jj].y;
    }
    o0 += __shfl_xor(o0, 16, 64); o0 += __shfl_xor(o0, 32, 64);
    o1 += __shfl_xor(o1, 16, 64); o1 += __shfl_xor(o1, 32, 64);
    const int i = a*16 + ty, j = b*16 + q;
    if (lane < 16 && j > i) {
      long p = (long)i*NN - (long)i*(i+1)/2 + (j - i - 1);
      out[(long)g*NPAIR + p] = make_float2(o0 + b30, o1 + b31);
    }
  }
}

extern "C" void kernel_launch(void* const* d_in, const int* in_sizes, int n_in,
                              void* d_out, int out_size, void* d_ws, size_t ws_size,
                              hipStream_t stream)
{
  const float* feat0  = (const float*)d_in[0];
  const float* feat1  = (const float*)d_in[1];
  const float* ec1_w1 = (const float*)d_in[2];
  const float* ec1_b1 = (const float*)d_in[3];
  const float* ec1_w2 = (const float*)d_in[4];
  const float* ec1_b2 = (const float*)d_in[5];
  const float* ec2_w1 = (const float*)d_in[6];
  const float* ec2_b1 = (const float*)d_in[7];
  const float* ec2_w2 = (const float*)d_in[8];
  const float* ec2_b2 = (const float*)d_in[9];
  const float* bn_g   = (const float*)d_in[10];
  const float* bn_b   = (const float*)d_in[11];
  const float* lin1_w = (const float*)d_in[12];
  const float* lin1_b = (const float*)d_in[13];
  const float* lin2_w = (const float*)d_in[14];
  const float* lin2_b = (const float*)d_in[15];
  const float* lin3_w = (const float*)d_in[16];
  const float* lin3_b = (const float*)d_in[17];

  char* ws = (char*)d_ws;
  int*   idx = (int*)  (ws + 0);
  float* e1  = (float*)(ws + 49152);
  float* e2  = (float*)(ws + 245760);
  float* u   = (float*)(ws + 442368);
  float* v   = (float*)(ws + 638976);
  float* mu  = (float*)(ws + 835584);
  float* sg  = (float*)(ws + 836640);
  float* c0g = (float*)(ws + 837696);

  topk_ec1_kernel<<<dim3(768,2), 64, 0, stream>>>(feat0, feat1, ec1_w1, ec1_b1,
                                                  ec1_w2, ec1_b2, idx, e1);
  ec2_kernel<<<dim3(768,2), 64, 0, stream>>>(idx, e1, ec2_w1, ec2_b1,
                                             ec2_w2, ec2_b2, e2);
  stats_kernel<<<dim3(132), 256, 0, stream>>>(feat0, feat1, e1, e2, bn_g, mu, sg);
  uv_c0_kernel<<<dim3(769,2), 64, 0, stream>>>(feat0, feat1, e1, e2, sg, mu, bn_b,
                                               lin1_w, lin1_b, u, v, c0g);
  pair_kernel<<<dim3(1176,2), 256, 0, stream>>>(u, v, c0g, lin2_w, lin2_b,
                                                lin3_w, lin3_b, (float2*)d_out);
}

// Round 4
// 136.251 us; speedup vs baseline: 1.2982x; 1.0219x over previous
//
#include <hip/hip_runtime.h>

#define NN 768
#define IN_F 68
#define KNN 8
#define EO 32
#define FEAT 264
#define HALF_FEAT 132
#define EMB 32
#define NPAIR 294528   // 768*767/2

typedef __attribute__((ext_vector_type(8))) short bf16x8;
typedef __attribute__((ext_vector_type(4))) float f32x4;

// pack hi16(x1):hi16(x0) into one dword — bf16 truncation of two floats, 1 v_perm
static __device__ __forceinline__ int pack_chop2(float x0, float x1) {
  return __builtin_amdgcn_perm(__float_as_uint(x1), __float_as_uint(x0), 0x07060302);
}
static __device__ __forceinline__ float chop(float x) {
  return __uint_as_float(__float_as_uint(x) & 0xffff0000u);
}

// ---------------- Kernel A: top-8 neighbors (stable, jax top_k semantics) + EdgeConv1 ----
__global__ void __launch_bounds__(64) topk_ec1_kernel(
    const float* __restrict__ feat0, const float* __restrict__ feat1,
    const float* __restrict__ w1, const float* __restrict__ b1,
    const float* __restrict__ w2, const float* __restrict__ b2,
    int* __restrict__ idx_out, float* __restrict__ e1out)
{
  const int i = blockIdx.x, g = blockIdx.y;
  const float* __restrict__ feat = g ? feat1 : feat0;
  const int lane = threadIdx.x;

  __shared__ unsigned long long keys[64*8];
  __shared__ int nbr[8];
  __shared__ float gl[KNN*IN_F];
  __shared__ float hsh[EO];

  const float4 ci = *(const float4*)(feat + i*IN_F);

  float4 cand[12];
#pragma unroll
  for (int t = 0; t < 12; t++)
    cand[t] = *(const float4*)(feat + (lane + 64*t)*IN_F);

  float bd[8]; int bidx[8];
#pragma unroll
  for (int k = 0; k < 8; k++) { bd[k] = 1e30f; bidx[k] = 0; }
#pragma unroll
  for (int t = 0; t < 12; t++) {
    const int j = lane + 64*t;
    float d = fabsf(ci.x - cand[t].x);   // same sequential add order as ref sum(-1)
    d += fabsf(ci.y - cand[t].y);
    d += fabsf(ci.z - cand[t].z);
    d += fabsf(ci.w - cand[t].w);
    if (d < bd[7]) {
#pragma unroll
      for (int k = 7; k >= 1; k--) {
        if (d < bd[k-1])    { bd[k] = bd[k-1]; bidx[k] = bidx[k-1]; }
        else if (d < bd[k]) { bd[k] = d;       bidx[k] = j; }
      }
      if (d < bd[0]) { bd[0] = d; bidx[0] = j; }
    }
  }
#pragma unroll
  for (int k = 0; k < 8; k++)
    keys[lane*8+k] = ((unsigned long long)__float_as_uint(bd[k]) << 32) | (unsigned)bidx[k];
  __syncthreads();
  int pos = 0;
#pragma unroll
  for (int r = 0; r < 8; r++) {
    unsigned long long mykey = keys[lane*8 + pos];
    unsigned long long mn = mykey;
#pragma unroll
    for (int s = 32; s >= 1; s >>= 1) {
      unsigned long long o = __shfl_xor(mn, s, 64);
      mn = (o < mn) ? o : mn;
    }
    if (mykey == mn) pos++;
    if (lane == 0) {
      int nb = (int)(mn & 0xffffffffull);
      nbr[r] = nb;
      idx_out[(g*NN+i)*8 + r] = nb;
    }
  }
  __syncthreads();

  for (int z = lane; z < KNN*17; z += 64) {
    int k = z / 17, q = z - k*17;
    *(float4*)&gl[k*IN_F + q*4] = *(const float4*)(feat + nbr[k]*IN_F + q*4);
  }
  __syncthreads();

  // layer1, 8 independent accumulator chains (k-major) for ILP
  const int e = lane & 31, hf = lane >> 5;
  float ak[8];
#pragma unroll
  for (int k = 0; k < 8; k++) ak[k] = 0.f;
  const int cbeg = hf*34;
  for (int c = cbeg; c < cbeg+34; c++) {
#pragma unroll
    for (int k = 0; k < 8; k++)
      ak[k] += gl[k*IN_F+c] * w1[(c*8+k)*EO + e];
  }
  float acc = ((ak[0]+ak[1])+(ak[2]+ak[3])) + ((ak[4]+ak[5])+(ak[6]+ak[7]));
  acc += __shfl_xor(acc, 32, 64);
  if (hf == 0) {
    float h = acc + b1[e];
    hsh[e] = fmaxf(h, 0.01f*h);
  }
  __syncthreads();
  if (lane < 32) {
    float o0=0.f, o1=0.f, o2=0.f, o3=0.f;
#pragma unroll
    for (int m = 0; m < 32; m += 4) {
      o0 += hsh[m+0] * w2[(m+0)*EO + lane];
      o1 += hsh[m+1] * w2[(m+1)*EO + lane];
      o2 += hsh[m+2] * w2[(m+2)*EO + lane];
      o3 += hsh[m+3] * w2[(m+3)*EO + lane];
    }
    float o = b2[lane] + ((o0+o1)+(o2+o3));
    o = fmaxf(o, 0.01f*o);
    e1out[(g*NN+i)*EO + lane] = o;
  }
}

// ---------------- Kernel B: EdgeConv2 ----------------
__global__ void __launch_bounds__(64) ec2_kernel(
    const int* __restrict__ idx, const float* __restrict__ e1,
    const float* __restrict__ w1, const float* __restrict__ b1,
    const float* __restrict__ w2, const float* __restrict__ b2,
    float* __restrict__ e2out)
{
  const int i = blockIdx.x, g = blockIdx.y;
  const int lane = threadIdx.x;
  __shared__ float gl[KNN*EO];
  __shared__ float hsh[EO];
  {
    const int k = lane >> 3, q = lane & 7;
    const int nb = idx[(g*NN+i)*8 + k];
    *(float4*)&gl[k*EO + q*4] = *(const float4*)(e1 + (g*NN+nb)*EO + q*4);
  }
  __syncthreads();
  const int e = lane & 31, hf = lane >> 5;
  float ak[8];
#pragma unroll
  for (int k = 0; k < 8; k++) ak[k] = 0.f;
  const int cbeg = hf*16;
  for (int c = cbeg; c < cbeg+16; c++) {
#pragma unroll
    for (int k = 0; k < 8; k++)
      ak[k] += gl[k*EO+c] * w1[(c*8+k)*EO + e];
  }
  float acc = ((ak[0]+ak[1])+(ak[2]+ak[3])) + ((ak[4]+ak[5])+(ak[6]+ak[7]));
  acc += __shfl_xor(acc, 32, 64);
  if (hf == 0) {
    float h = acc + b1[e];
    hsh[e] = fmaxf(h, 0.01f*h);
  }
  __syncthreads();
  if (lane < 32) {
    float o0=0.f, o1=0.f, o2=0.f, o3=0.f;
#pragma unroll
    for (int m = 0; m < 32; m += 4) {
      o0 += hsh[m+0] * w2[(m+0)*EO + lane];
      o1 += hsh[m+1] * w2[(m+1)*EO + lane];
      o2 += hsh[m+2] * w2[(m+2)*EO + lane];
      o3 += hsh[m+3] * w2[(m+3)*EO + lane];
    }
    float o = b2[lane] + ((o0+o1)+(o2+o3));
    o = fmaxf(o, 0.01f*o);
    e2out[(g*NN+i)*EO + lane] = o;
  }
}

// ---------------- Kernel C: BN stats (weighted node sums, shfl reduce) ----------------
__global__ void __launch_bounds__(256) stats_kernel(
    const float* __restrict__ feat0, const float* __restrict__ feat1,
    const float* __restrict__ e1, const float* __restrict__ e2,
    const float* __restrict__ bn_g,
    float* __restrict__ mu_out, float* __restrict__ sg_out)
{
  const int c = blockIdx.x;   // 0..131
  const int tid = threadIdx.x;
  double s1=0, s2=0, q1=0, q2=0;
  for (int t = tid; t < 2*NN; t += 256) {
    int g = t >= NN;
    int i = t - g*NN;
    float val;
    if (c < IN_F)      val = (g ? feat1 : feat0)[i*IN_F + c];
    else if (c < 100)  val = e1[(g*NN+i)*EO + (c-IN_F)];
    else               val = e2[(g*NN+i)*EO + (c-100)];
    double dv = val;
    double wf = (double)(NN-1-i), wsnd = (double)i;
    s1 += wf*dv;  s2 += wsnd*dv;
    double dq = dv*dv;
    q1 += wf*dq;  q2 += wsnd*dq;
  }
#pragma unroll
  for (int off = 32; off >= 1; off >>= 1) {
    s1 += __shfl_xor(s1, off, 64);
    s2 += __shfl_xor(s2, off, 64);
    q1 += __shfl_xor(q1, off, 64);
    q2 += __shfl_xor(q2, off, 64);
  }
  __shared__ double red[4][4];
  const int w = tid >> 6;
  if ((tid & 63) == 0) { red[w][0]=s1; red[w][1]=s2; red[w][2]=q1; red[w][3]=q2; }
  __syncthreads();
  if (tid == 0) {
    double t0 = red[0][0]+red[1][0]+red[2][0]+red[3][0];
    double t1 = red[0][1]+red[1][1]+red[2][1]+red[3][1];
    double t2 = red[0][2]+red[1][2]+red[2][2]+red[3][2];
    double t3 = red[0][3]+red[1][3]+red[2][3]+red[3][3];
    const double M2 = 2.0 * (double)NPAIR;
    double mu1 = t0/M2, mu2 = t1/M2;
    double v1 = t2/M2 - mu1*mu1;
    double v2 = t3/M2 - mu2*mu2;
    mu_out[c]           = (float)mu1;
    mu_out[HALF_FEAT+c] = (float)mu2;
    sg_out[c]           = (float)((double)bn_g[c] / sqrt(v1 + 1e-5));
    sg_out[HALF_FEAT+c] = (float)((double)bn_g[HALF_FEAT+c] / sqrt(v2 + 1e-5));
  }
}

// ---------------- Kernel D: per-node u/v, plus c0 ----------------
__global__ void __launch_bounds__(64) uv_c0_kernel(
    const float* __restrict__ feat0, const float* __restrict__ feat1,
    const float* __restrict__ e1, const float* __restrict__ e2,
    const float* __restrict__ sg, const float* __restrict__ mu,
    const float* __restrict__ bn_b,
    const float* __restrict__ lin1_w, const float* __restrict__ lin1_b,
    float* __restrict__ u, float* __restrict__ v, float* __restrict__ c0g)
{
  const int i = blockIdx.x, g = blockIdx.y;
  const int t = threadIdx.x;
  if (i == NN) {
    if (g == 0 && t < EMB) {
      float a0=0.f, a1=0.f, a2=0.f, a3=0.f;
      for (int c = 0; c < FEAT; c += 4) {
        a0 += (bn_b[c+0] - mu[c+0]*sg[c+0]) * lin1_w[(c+0)*EMB + t];
        a1 += (bn_b[c+1] - mu[c+1]*sg[c+1]) * lin1_w[(c+1)*EMB + t];
        a2 += (bn_b[c+2] - mu[c+2]*sg[c+2]) * lin1_w[(c+2)*EMB + t];
        a3 += (bn_b[c+3] - mu[c+3]*sg[c+3]) * lin1_w[(c+3)*EMB + t];
      }
      c0g[t] = lin1_b[t] + ((a0+a1)+(a2+a3));
    }
    return;
  }
  __shared__ float x[HALF_FEAT];
  for (int c = t; c < IN_F; c += 64) x[c] = (g ? feat1 : feat0)[i*IN_F + c];
  if (t < 32) x[IN_F + t]     = e1[(g*NN+i)*EO + t];
  else        x[100 + (t-32)] = e2[(g*NN+i)*EO + (t-32)];
  __syncthreads();
  const int e = t & 31, hf = t >> 5;
  const int base = hf * HALF_FEAT;
  float a0=0.f, a1=0.f, a2=0.f, a3=0.f;
  for (int c = 0; c < HALF_FEAT; c += 4) {
    a0 += x[c+0] * sg[base+c+0] * lin1_w[(base+c+0)*EMB + e];
    a1 += x[c+1] * sg[base+c+1] * lin1_w[(base+c+1)*EMB + e];
    a2 += x[c+2] * sg[base+c+2] * lin1_w[(base+c+2)*EMB + e];
    a3 += x[c+3] * sg[base+c+3] * lin1_w[(base+c+3)*EMB + e];
  }
  float acc = ((a0+a1)+(a2+a3));
  float* dst = hf ? v : u;
  dst[(g*NN+i)*EMB + e] = acc;
}

// ---------------- Kernel E: pair MLP via split-bf16 MFMA ----------------
// Split = truncate-to-bf16 + exact fp32 residual (chop is exact; residual is a
// same-exponent subtract -> exact). Dropped terms ~2^-16 relative. Packing two
// hi-halves per dword is a single v_perm_b32.
__global__ void __launch_bounds__(256) pair_kernel(
    const float* __restrict__ u, const float* __restrict__ v,
    const float* __restrict__ c0g,
    const float* __restrict__ lin2_w, const float* __restrict__ lin2_b,
    const float* __restrict__ lin3_w, const float* __restrict__ lin3_b,
    float2* __restrict__ out)
{
  const int g = blockIdx.y;
  int rem = blockIdx.x;        // 0..1175 triangular tile id
  int a = 0;
  while (rem >= 48 - a) { rem -= 48 - a; a++; }
  const int b = a + rem;

  __shared__ float su[16*36], sv[16*36];
  __shared__ float wbuf[4][16*36];
  const int tid = threadIdx.x;
  {
    int r = tid >> 5, c = tid & 31;
    su[r*36+c] = u[(g*NN + a*16 + r)*EMB + c];
    sv[r*36+c] = v[(g*NN + b*16 + r)*EMB + c];
    r += 8;
    su[r*36+c] = u[(g*NN + a*16 + r)*EMB + c];
    sv[r*36+c] = v[(g*NN + b*16 + r)*EMB + c];
  }
  __syncthreads();

  const int lane = tid & 63, w = tid >> 6;
  const int q = lane & 15, kg = lane >> 4;   // q: m/n index, kg: k-group

  // W2 fragments (B operand: n = lane&15, k = kg*8+jj), chop/residual split
  union { int i[4]; bf16x8 v; } whi0, wlo0, whi1, wlo1;
#pragma unroll
  for (int d = 0; d < 4; d++) {
    float w0a = lin2_w[(kg*8+2*d)*32 + q],      w0b = lin2_w[(kg*8+2*d+1)*32 + q];
    float w1a = lin2_w[(kg*8+2*d)*32 + 16 + q], w1b = lin2_w[(kg*8+2*d+1)*32 + 16 + q];
    whi0.i[d] = pack_chop2(w0a, w0b);
    wlo0.i[d] = pack_chop2(w0a - chop(w0a), w0b - chop(w0b));
    whi1.i[d] = pack_chop2(w1a, w1b);
    wlo1.i[d] = pack_chop2(w1a - chop(w1a), w1b - chop(w1b));
  }
  // sv + c0 for this lane's (m=q, k=kg*8+jj) — tile-invariant
  float svc[8];
#pragma unroll
  for (int jj = 0; jj < 8; jj++)
    svc[jj] = sv[q*36 + kg*8 + jj] + c0g[kg*8+jj];
  // epilogue constants for this lane's n-range
  float2 w3v[8]; float b2v[8];
#pragma unroll
  for (int jj = 0; jj < 8; jj++) {
    w3v[jj] = ((const float2*)lin3_w)[kg*8+jj];
    b2v[jj] = lin2_b[kg*8+jj];
  }
  const float b30 = lin3_b[0], b31 = lin3_b[1];

  float* wb = wbuf[w];
#pragma unroll
  for (int t = 0; t < 4; t++) {
    const int ty = w*4 + t;
    // A fragment: rows m = 16 j-nodes, k = embedding dim; chop/residual split
    const float4 sa = *(const float4*)&su[ty*36 + kg*8];
    const float4 sb = *(const float4*)&su[ty*36 + kg*8 + 4];
    float se[8] = {sa.x, sa.y, sa.z, sa.w, sb.x, sb.y, sb.z, sb.w};
    union { int i[4]; bf16x8 v; } ahi, alo;
#pragma unroll
    for (int d = 0; d < 4; d++) {
      float s0 = se[2*d]   + svc[2*d];
      float s1 = se[2*d+1] + svc[2*d+1];
      s0 = fmaxf(s0, 0.01f*s0);
      s1 = fmaxf(s1, 0.01f*s1);
      ahi.i[d] = pack_chop2(s0, s1);
      alo.i[d] = pack_chop2(s0 - chop(s0), s1 - chop(s1));
    }
    f32x4 acc0 = {0.f,0.f,0.f,0.f}, acc1 = {0.f,0.f,0.f,0.f};
    acc0 = __builtin_amdgcn_mfma_f32_16x16x32_bf16(ahi.v, whi0.v, acc0, 0,0,0);
    acc1 = __builtin_amdgcn_mfma_f32_16x16x32_bf16(ahi.v, whi1.v, acc1, 0,0,0);
    acc0 = __builtin_amdgcn_mfma_f32_16x16x32_bf16(ahi.v, wlo0.v, acc0, 0,0,0);
    acc1 = __builtin_amdgcn_mfma_f32_16x16x32_bf16(ahi.v, wlo1.v, acc1, 0,0,0);
    acc0 = __builtin_amdgcn_mfma_f32_16x16x32_bf16(alo.v, whi0.v, acc0, 0,0,0);
    acc1 = __builtin_amdgcn_mfma_f32_16x16x32_bf16(alo.v, whi1.v, acc1, 0,0,0);
    // D layout: row m = kg*4+r, col n = q (acc0: n<16, acc1: n>=16)
#pragma unroll
    for (int r = 0; r < 4; r++) {
      wb[(kg*4+r)*36 + q]      = acc0[r];
      wb[(kg*4+r)*36 + 16 + q] = acc1[r];
    }
    // epilogue: lane handles pair m=q, n-range kg*8..kg*8+8
    float o0 = 0.f, o1 = 0.f;
#pragma unroll
    for (int jj = 0; jj < 8; jj++) {
      float h = wb[q*36 + kg*8 + jj] + b2v[jj];
      h = fmaxf(h, 0.01f*h);
      o0 += h * w3v[jj].x;
      o1 += h * w3v[jj].y;
    }
    o0 += __shfl_xor(o0, 16, 64); o0 += __shfl_xor(o0, 32, 64);
    o1 += __shfl_xor(o1, 16, 64); o1 += __shfl_xor(o1, 32, 64);
    const int i = a*16 + ty, j = b*16 + q;
    if (lane < 16 && j > i) {
      long p = (long)i*NN - (long)i*(i+1)/2 + (j - i - 1);
      out[(long)g*NPAIR + p] = make_float2(o0 + b30, o1 + b31);
    }
  }
}

extern "C" void kernel_launch(void* const* d_in, const int* in_sizes, int n_in,
                              void* d_out, int out_size, void* d_ws, size_t ws_size,
                              hipStream_t stream)
{
  const float* feat0  = (const float*)d_in[0];
  const float* feat1  = (const float*)d_in[1];
  const float* ec1_w1 = (const float*)d_in[2];
  const float* ec1_b1 = (const float*)d_in[3];
  const float* ec1_w2 = (const float*)d_in[4];
  const float* ec1_b2 = (const float*)d_in[5];
  const float* ec2_w1 = (const float*)d_in[6];
  const float* ec2_b1 = (const float*)d_in[7];
  const float* ec2_w2 = (const float*)d_in[8];
  const float* ec2_b2 = (const float*)d_in[9];
  const float* bn_g   = (const float*)d_in[10];
  const float* bn_b   = (const float*)d_in[11];
  const float* lin1_w = (const float*)d_in[12];
  const float* lin1_b = (const float*)d_in[13];
  const float* lin2_w = (const float*)d_in[14];
  const float* lin2_b = (const float*)d_in[15];
  const float* lin3_w = (const float*)d_in[16];
  const float* lin3_b = (const float*)d_in[17];

  char* ws = (char*)d_ws;
  int*   idx = (int*)  (ws + 0);
  float* e1  = (float*)(ws + 49152);
  float* e2  = (float*)(ws + 245760);
  float* u   = (float*)(ws + 442368);
  float* v   = (float*)(ws + 638976);
  float* mu  = (float*)(ws + 835584);
  float* sg  = (float*)(ws + 836640);
  float* c0g = (float*)(ws + 837696);

  topk_ec1_kernel<<<dim3(768,2), 64, 0, stream>>>(feat0, feat1, ec1_w1, ec1_b1,
                                                  ec1_w2, ec1_b2, idx, e1);
  ec2_kernel<<<dim3(768,2), 64, 0, stream>>>(idx, e1, ec2_w1, ec2_b1,
                                             ec2_w2, ec2_b2, e2);
  stats_kernel<<<dim3(132), 256, 0, stream>>>(feat0, feat1, e1, e2, bn_g, mu, sg);
  uv_c0_kernel<<<dim3(769,2), 64, 0, stream>>>(feat0, feat1, e1, e2, sg, mu, bn_b,
                                               lin1_w, lin1_b, u, v, c0g);
  pair_kernel<<<dim3(1176,2), 256, 0, stream>>>(u, v, c0g, lin2_w, lin2_b,
                                                lin3_w, lin3_b, (float2*)d_out);
}